// Round 1
// baseline (1185.145 us; speedup 1.0000x reference)
//
#include <hip/hip_runtime.h>

#define N_PER 32768
#define STRIDE_ST 68          // padded LDS row stride (words): j*68 mod 32 = j*4 -> conflict-free
#define KVSZ 288              // per-cloud accum: 256 kv[h][d][e] + 32 ksum[h][d]
#define EPS_LN 1e-5f
#define EPS_Z  1e-6f

__device__ __forceinline__ void cpw(float* dst, const float* __restrict__ src, int n, int tid) {
  for (int i = tid; i < n; i += 256) dst[i] = src[i];
}

// out[j] = b[j] + sum_k h[k] * w[k*32+j]
__device__ __forceinline__ void proj32(const float* h, const float* w, const float* b, float* out) {
#pragma unroll
  for (int j = 0; j < 32; j++) out[j] = b[j];
#pragma unroll
  for (int k = 0; k < 32; k++) {
    float hk = h[k];
#pragma unroll
    for (int j = 0; j < 32; j++) out[j] = fmaf(hk, w[k*32 + j], out[j]);
  }
}

// phi(x) = elu(x)+1 = x>0 ? x+1 : exp(x)
__device__ __forceinline__ void phi32(float* a) {
#pragma unroll
  for (int j = 0; j < 32; j++) a[j] = a[j] > 0.f ? a[j] + 1.f : expf(a[j]);
}

__device__ __forceinline__ void ln32(float* h, const float* g, const float* b) {
  float mu = 0.f;
#pragma unroll
  for (int j = 0; j < 32; j++) mu += h[j];
  mu *= (1.f / 32.f);
  float var = 0.f;
#pragma unroll
  for (int j = 0; j < 32; j++) { float d = h[j] - mu; var = fmaf(d, d, var); }
  var *= (1.f / 32.f);
  float r = rsqrtf(var + EPS_LN);
#pragma unroll
  for (int j = 0; j < 32; j++) h[j] = (h[j] - mu) * r * g[j] + b[j];
}

// attn[h*8+e] = z_h * sum_d q[h*8+d] * kv[h][d][e],  z_h = 1/(q.ksum_h + eps)
__device__ __forceinline__ void attn_part(const float* q, const float* kvl, float* attn) {
#pragma unroll
  for (int hh = 0; hh < 4; hh++) {
    float dot = 0.f;
#pragma unroll
    for (int d = 0; d < 8; d++) dot = fmaf(q[hh*8 + d], kvl[256 + hh*8 + d], dot);
    float zr = 1.f / (dot + EPS_Z);
#pragma unroll
    for (int e = 0; e < 8; e++) {
      float s = 0.f;
#pragma unroll
      for (int d = 0; d < 8; d++) s = fmaf(q[hh*8 + d], kvl[hh*64 + d*8 + e], s);
      attn[hh*8 + e] = s * zr;
    }
  }
}

// out[j] = bf2[j] + sum_k relu(hid_k) * w2[k*32+j],  hid = h@w1 + bf1 (hidden = 64, 2 chunks)
__device__ __forceinline__ void ffn32(const float* h, const float* w1, const float* b1,
                                      const float* w2, const float* b2, float* out) {
#pragma unroll
  for (int j = 0; j < 32; j++) out[j] = b2[j];
#pragma unroll
  for (int cchunk = 0; cchunk < 2; cchunk++) {
    float hid[32];
#pragma unroll
    for (int j = 0; j < 32; j++) hid[j] = b1[cchunk*32 + j];
#pragma unroll
    for (int k = 0; k < 32; k++) {
      float hk = h[k];
#pragma unroll
      for (int j = 0; j < 32; j++) hid[j] = fmaf(hk, w1[k*64 + cchunk*32 + j], hid[j]);
    }
#pragma unroll
    for (int k = 0; k < 32; k++) {
      float hk = fmaxf(hid[k], 0.f);
#pragma unroll
      for (int j = 0; j < 32; j++) out[j] = fmaf(hk, w2[(cchunk*32 + k)*32 + j], out[j]);
    }
  }
}

// Per-wave LDS transpose-stage reduction of kv = sum k (x) v and ksum = sum k.
// Lane (d,e) = (lane>>3, lane&7) owns kv[h][d][e] for all 4 heads.
__device__ __forceinline__ void accum_kv(const float* kk, const float* vv,
                                         float* stg, float* blk, float* gkv, int tid) {
  const int lane = tid & 63;
  const int down = lane >> 3;
  const int eown = lane & 7;
  float kvacc[4], ksacc[4];
#pragma unroll
  for (int hh = 0; hh < 4; hh++) {
#pragma unroll
    for (int j = 0; j < 8; j++) {
      stg[j*STRIDE_ST + lane]       = kk[hh*8 + j];
      stg[(8 + j)*STRIDE_ST + lane] = vv[hh*8 + j];
    }
    __syncthreads();
    float acc = 0.f, ks = 0.f;
#pragma unroll
    for (int p = 0; p < 64; p += 4) {
      const float4 kf = *(const float4*)&stg[down*STRIDE_ST + p];
      const float4 vf = *(const float4*)&stg[(8 + eown)*STRIDE_ST + p];
      acc = fmaf(kf.x, vf.x, acc);
      acc = fmaf(kf.y, vf.y, acc);
      acc = fmaf(kf.z, vf.z, acc);
      acc = fmaf(kf.w, vf.w, acc);
      ks += (kf.x + kf.y) + (kf.z + kf.w);
    }
    kvacc[hh] = acc;
    ksacc[hh] = ks;
    __syncthreads();
  }
#pragma unroll
  for (int hh = 0; hh < 4; hh++)
    atomicAdd(&blk[hh*64 + down*8 + eown], kvacc[hh]);
  if (eown == 0) {
#pragma unroll
    for (int hh = 0; hh < 4; hh++)
      atomicAdd(&blk[256 + hh*8 + down], ksacc[hh]);
  }
  __syncthreads();
  for (int i = tid; i < KVSZ; i += 256) atomicAdd(&gkv[i], blk[i]);
}

// K1: embed -> h0 (to d_out), k/v layer0 -> kv accum
__global__ __launch_bounds__(256) void k_embed(
    const float* __restrict__ x, const float* __restrict__ pos,
    const float* __restrict__ w_in, const float* __restrict__ b_in,
    const float* __restrict__ w_pos, const float* __restrict__ b_pos,
    const float* __restrict__ wk, const float* __restrict__ bk,
    const float* __restrict__ wv, const float* __restrict__ bv,
    float* __restrict__ hout, float* __restrict__ gkv) {
  __shared__ __align__(16) float wl[2784];
  __shared__ __align__(16) float stage[4 * 16 * STRIDE_ST];
  __shared__ float blk[KVSZ];
  const int tid = threadIdx.x;
  cpw(wl,        w_in,  512, tid);
  cpw(wl + 512,  b_in,   32, tid);
  cpw(wl + 544,  w_pos,  96, tid);
  cpw(wl + 640,  b_pos,  32, tid);
  cpw(wl + 672,  wk,   1024, tid);
  cpw(wl + 1696, bk,     32, tid);
  cpw(wl + 1728, wv,   1024, tid);
  cpw(wl + 2752, bv,     32, tid);
  for (int i = tid; i < KVSZ; i += 256) blk[i] = 0.f;
  __syncthreads();

  const int pt = blockIdx.x * 256 + tid;
  const int c  = blockIdx.x >> 7;   // 128 blocks per cloud

  float xin[16];
  const float4* xp = (const float4*)(x + (size_t)pt * 16);
#pragma unroll
  for (int q4 = 0; q4 < 4; q4++) {
    float4 t = xp[q4];
    xin[q4*4] = t.x; xin[q4*4+1] = t.y; xin[q4*4+2] = t.z; xin[q4*4+3] = t.w;
  }
  float p0 = pos[(size_t)pt*3], p1 = pos[(size_t)pt*3+1], p2 = pos[(size_t)pt*3+2];

  float h[32];
#pragma unroll
  for (int j = 0; j < 32; j++) h[j] = wl[512 + j] + wl[640 + j];
#pragma unroll
  for (int k = 0; k < 16; k++) {
    float hk = xin[k];
#pragma unroll
    for (int j = 0; j < 32; j++) h[j] = fmaf(hk, wl[k*32 + j], h[j]);
  }
#pragma unroll
  for (int j = 0; j < 32; j++) {
    h[j] = fmaf(p0, wl[544 + j], h[j]);
    h[j] = fmaf(p1, wl[576 + j], h[j]);
    h[j] = fmaf(p2, wl[608 + j], h[j]);
  }
  float4* ho = (float4*)(hout + (size_t)pt * 32);
#pragma unroll
  for (int q4 = 0; q4 < 8; q4++) {
    float4 t; t.x = h[q4*4]; t.y = h[q4*4+1]; t.z = h[q4*4+2]; t.w = h[q4*4+3];
    ho[q4] = t;
  }
  float kk[32], vv[32];
  proj32(h, wl + 672,  wl + 1696, kk);
  phi32(kk);
  proj32(h, wl + 1728, wl + 2752, vv);
  accum_kv(kk, vv, stage + (tid >> 6) * (16 * STRIDE_ST), blk, gkv + c * KVSZ, tid);
}

// K2: layer-0 attention+FFN (reads/writes hbuf in place), layer-1 k/v -> kv accum
__global__ __launch_bounds__(256) void k_mid(
    const float* __restrict__ wq, const float* __restrict__ bq,
    const float* __restrict__ wo, const float* __restrict__ bo,
    const float* __restrict__ g1, const float* __restrict__ be1,
    const float* __restrict__ w1, const float* __restrict__ bf1,
    const float* __restrict__ w2, const float* __restrict__ bf2,
    const float* __restrict__ g2, const float* __restrict__ be2,
    const float* __restrict__ wkn, const float* __restrict__ bkn,
    const float* __restrict__ wvn, const float* __restrict__ bvn,
    const float* __restrict__ kv_in, float* __restrict__ gkv_out,
    float* __restrict__ hbuf) {
  __shared__ __align__(16) float wl[8544];
  __shared__ __align__(16) float kvl[KVSZ];
  __shared__ __align__(16) float stage[4 * 16 * STRIDE_ST];
  __shared__ float blk[KVSZ];
  const int tid = threadIdx.x;
  const int c   = blockIdx.x >> 7;
  cpw(wl,        wq,  1024, tid);
  cpw(wl + 1024, bq,    32, tid);
  cpw(wl + 1056, wo,  1024, tid);
  cpw(wl + 2080, bo,    32, tid);
  cpw(wl + 2112, g1,    32, tid);
  cpw(wl + 2144, be1,   32, tid);
  cpw(wl + 2176, w1,  2048, tid);
  cpw(wl + 4224, bf1,   64, tid);
  cpw(wl + 4288, w2,  2048, tid);
  cpw(wl + 6336, bf2,   32, tid);
  cpw(wl + 6368, g2,    32, tid);
  cpw(wl + 6400, be2,   32, tid);
  cpw(wl + 6432, wkn, 1024, tid);
  cpw(wl + 7456, bkn,   32, tid);
  cpw(wl + 7488, wvn, 1024, tid);
  cpw(wl + 8512, bvn,   32, tid);
  cpw(kvl, kv_in + c * KVSZ, KVSZ, tid);
  for (int i = tid; i < KVSZ; i += 256) blk[i] = 0.f;
  __syncthreads();

  const int pt = blockIdx.x * 256 + tid;
  float h[32];
  const float4* hp = (const float4*)(hbuf + (size_t)pt * 32);
#pragma unroll
  for (int q4 = 0; q4 < 8; q4++) {
    float4 t = hp[q4];
    h[q4*4] = t.x; h[q4*4+1] = t.y; h[q4*4+2] = t.z; h[q4*4+3] = t.w;
  }
  float qv[32];
  proj32(h, wl, wl + 1024, qv);
  phi32(qv);
  float attn[32];
  attn_part(qv, kvl, attn);
  float o[32];
  proj32(attn, wl + 1056, wl + 2080, o);
#pragma unroll
  for (int j = 0; j < 32; j++) h[j] += o[j];
  ln32(h, wl + 2112, wl + 2144);
  float f[32];
  ffn32(h, wl + 2176, wl + 4224, wl + 4288, wl + 6336, f);
#pragma unroll
  for (int j = 0; j < 32; j++) h[j] += f[j];
  ln32(h, wl + 6368, wl + 6400);
  float4* hpw = (float4*)(hbuf + (size_t)pt * 32);
#pragma unroll
  for (int q4 = 0; q4 < 8; q4++) {
    float4 t; t.x = h[q4*4]; t.y = h[q4*4+1]; t.z = h[q4*4+2]; t.w = h[q4*4+3];
    hpw[q4] = t;
  }
  float kk[32], vv[32];
  proj32(h, wl + 6432, wl + 7456, kk);
  phi32(kk);
  proj32(h, wl + 7488, wl + 8512, vv);
  accum_kv(kk, vv, stage + (tid >> 6) * (16 * STRIDE_ST), blk, gkv_out + c * KVSZ, tid);
}

// K3: layer-1 attention+FFN -> final output (in place in hbuf == d_out)
__global__ __launch_bounds__(256) void k_last(
    const float* __restrict__ wq, const float* __restrict__ bq,
    const float* __restrict__ wo, const float* __restrict__ bo,
    const float* __restrict__ g1, const float* __restrict__ be1,
    const float* __restrict__ w1, const float* __restrict__ bf1,
    const float* __restrict__ w2, const float* __restrict__ bf2,
    const float* __restrict__ g2, const float* __restrict__ be2,
    const float* __restrict__ kv_in, float* __restrict__ hbuf) {
  __shared__ __align__(16) float wl[6432];
  __shared__ __align__(16) float kvl[KVSZ];
  const int tid = threadIdx.x;
  const int c   = blockIdx.x >> 7;
  cpw(wl,        wq,  1024, tid);
  cpw(wl + 1024, bq,    32, tid);
  cpw(wl + 1056, wo,  1024, tid);
  cpw(wl + 2080, bo,    32, tid);
  cpw(wl + 2112, g1,    32, tid);
  cpw(wl + 2144, be1,   32, tid);
  cpw(wl + 2176, w1,  2048, tid);
  cpw(wl + 4224, bf1,   64, tid);
  cpw(wl + 4288, w2,  2048, tid);
  cpw(wl + 6336, bf2,   32, tid);
  cpw(wl + 6368, g2,    32, tid);
  cpw(wl + 6400, be2,   32, tid);
  cpw(kvl, kv_in + c * KVSZ, KVSZ, tid);
  __syncthreads();

  const int pt = blockIdx.x * 256 + tid;
  float h[32];
  const float4* hp = (const float4*)(hbuf + (size_t)pt * 32);
#pragma unroll
  for (int q4 = 0; q4 < 8; q4++) {
    float4 t = hp[q4];
    h[q4*4] = t.x; h[q4*4+1] = t.y; h[q4*4+2] = t.z; h[q4*4+3] = t.w;
  }
  float qv[32];
  proj32(h, wl, wl + 1024, qv);
  phi32(qv);
  float attn[32];
  attn_part(qv, kvl, attn);
  float o[32];
  proj32(attn, wl + 1056, wl + 2080, o);
#pragma unroll
  for (int j = 0; j < 32; j++) h[j] += o[j];
  ln32(h, wl + 2112, wl + 2144);
  float f[32];
  ffn32(h, wl + 2176, wl + 4224, wl + 4288, wl + 6336, f);
#pragma unroll
  for (int j = 0; j < 32; j++) h[j] += f[j];
  ln32(h, wl + 6368, wl + 6400);
  float4* hpw = (float4*)(hbuf + (size_t)pt * 32);
#pragma unroll
  for (int q4 = 0; q4 < 8; q4++) {
    float4 t; t.x = h[q4*4]; t.y = h[q4*4+1]; t.z = h[q4*4+2]; t.w = h[q4*4+3];
    hpw[q4] = t;
  }
}

extern "C" void kernel_launch(void* const* d_in, const int* in_sizes, int n_in,
                              void* d_out, int out_size, void* d_ws, size_t ws_size,
                              hipStream_t stream) {
  (void)in_sizes; (void)n_in; (void)out_size; (void)ws_size;
  const float* x     = (const float*)d_in[0];
  const float* pos   = (const float*)d_in[1];
  // d_in[2] = batch (arange//N_PER) -- identity mapping, unused
  const float* w_in  = (const float*)d_in[3];
  const float* b_in  = (const float*)d_in[4];
  const float* w_pos = (const float*)d_in[5];
  const float* b_pos = (const float*)d_in[6];
  const float* wq  = (const float*)d_in[7];
  const float* bq  = (const float*)d_in[8];
  const float* wk  = (const float*)d_in[9];
  const float* bk  = (const float*)d_in[10];
  const float* wv  = (const float*)d_in[11];
  const float* bv  = (const float*)d_in[12];
  const float* wo  = (const float*)d_in[13];
  const float* bo  = (const float*)d_in[14];
  const float* g1  = (const float*)d_in[15];
  const float* be1 = (const float*)d_in[16];
  const float* w1  = (const float*)d_in[17];
  const float* bf1 = (const float*)d_in[18];
  const float* w2  = (const float*)d_in[19];
  const float* bf2 = (const float*)d_in[20];
  const float* g2  = (const float*)d_in[21];
  const float* be2 = (const float*)d_in[22];
  float* out   = (float*)d_out;
  float* kvbuf = (float*)d_ws;   // 2 layers * 16 clouds * 288 floats = 36 KB

  hipMemsetAsync(kvbuf, 0, 2 * 16 * KVSZ * sizeof(float), stream);
  dim3 grid(2048), block(256);
  k_embed<<<grid, block, 0, stream>>>(x, pos, w_in, b_in, w_pos, b_pos,
                                      wk, bk, wv, bv, out, kvbuf);
  k_mid<<<grid, block, 0, stream>>>(wq, bq, wo, bo, g1, be1, w1, bf1, w2, bf2, g2, be2,
                                    wk + 1024, bk + 32, wv + 1024, bv + 32,
                                    kvbuf, kvbuf + 16 * KVSZ, out);
  k_last<<<grid, block, 0, stream>>>(wq + 1024, bq + 32, wo + 1024, bo + 32,
                                     g1 + 32, be1 + 32, w1 + 2048, bf1 + 64,
                                     w2 + 2048, bf2 + 32, g2 + 32, be2 + 32,
                                     kvbuf + 16 * KVSZ, out);
}

// Round 2
// 706.008 us; speedup vs baseline: 1.6787x; 1.6787x over previous
//
#include <hip/hip_runtime.h>

#define N_PER 32768
#define STRIDE_ST 68          // padded LDS row stride (words): conflict-free b32 writes + b128 reads
#define KVSZ 288              // per-cloud accum: 256 kv[h][d][e] + 32 ksum[h][d]
#define EPS_LN 1e-5f
#define EPS_Z  1e-6f

// out[j] = b[j] + sum_k h[k] * w[k*32+j]   (w, b wave-uniform -> s_load into SGPRs)
__device__ __forceinline__ void proj32(const float* h, const float* __restrict__ w,
                                       const float* __restrict__ b, float* out) {
#pragma unroll
  for (int j = 0; j < 32; j++) out[j] = b[j];
#pragma unroll
  for (int k = 0; k < 32; k++) {
    float hk = h[k];
#pragma unroll
    for (int j = 0; j < 32; j++) out[j] = fmaf(hk, w[k*32 + j], out[j]);
  }
}

// out[j] += b[j] + sum_k h[k] * w[k*32+j]   (residual-fused projection)
__device__ __forceinline__ void proj32_add(const float* h, const float* __restrict__ w,
                                           const float* __restrict__ b, float* out) {
#pragma unroll
  for (int j = 0; j < 32; j++) out[j] += b[j];
#pragma unroll
  for (int k = 0; k < 32; k++) {
    float hk = h[k];
#pragma unroll
    for (int j = 0; j < 32; j++) out[j] = fmaf(hk, w[k*32 + j], out[j]);
  }
}

// phi(x) = elu(x)+1 = x>0 ? x+1 : exp(x)
__device__ __forceinline__ void phi32(float* a) {
#pragma unroll
  for (int j = 0; j < 32; j++) a[j] = a[j] > 0.f ? a[j] + 1.f : __expf(a[j]);
}

__device__ __forceinline__ void ln32(float* h, const float* __restrict__ g,
                                     const float* __restrict__ b) {
  float mu = 0.f;
#pragma unroll
  for (int j = 0; j < 32; j++) mu += h[j];
  mu *= (1.f / 32.f);
  float var = 0.f;
#pragma unroll
  for (int j = 0; j < 32; j++) { float d = h[j] - mu; var = fmaf(d, d, var); }
  var *= (1.f / 32.f);
  float r = rsqrtf(var + EPS_LN);
#pragma unroll
  for (int j = 0; j < 32; j++) h[j] = (h[j] - mu) * r * g[j] + b[j];
}

// attn[h*8+e] = z_h * sum_d q[h*8+d] * kv[h][d][e],  z_h = 1/(q.ksum_h + eps)
// kvg is wave-uniform global memory (per-cloud summary) -> s_load
__device__ __forceinline__ void attn_part(const float* q, const float* __restrict__ kvg,
                                          float* attn) {
#pragma unroll
  for (int hh = 0; hh < 4; hh++) {
    float dot = 0.f;
#pragma unroll
    for (int d = 0; d < 8; d++) dot = fmaf(q[hh*8 + d], kvg[256 + hh*8 + d], dot);
    float zr = 1.f / (dot + EPS_Z);
#pragma unroll
    for (int e = 0; e < 8; e++) {
      float s = 0.f;
#pragma unroll
      for (int d = 0; d < 8; d++) s = fmaf(q[hh*8 + d], kvg[hh*64 + d*8 + e], s);
      attn[hh*8 + e] = s * zr;
    }
  }
}

// h[j] += bf2[j] + sum_k relu(hid_k) * w2[k*32+j],  hid = h@w1 + bf1 (hidden=64)
__device__ __forceinline__ void ffn32_add(float* h, const float* __restrict__ w1,
                                          const float* __restrict__ b1,
                                          const float* __restrict__ w2,
                                          const float* __restrict__ b2) {
  float hid[64];
#pragma unroll
  for (int j = 0; j < 64; j++) hid[j] = b1[j];
#pragma unroll
  for (int k = 0; k < 32; k++) {
    float hk = h[k];
#pragma unroll
    for (int j = 0; j < 64; j++) hid[j] = fmaf(hk, w1[k*64 + j], hid[j]);
  }
#pragma unroll
  for (int j = 0; j < 32; j++) h[j] += b2[j];
#pragma unroll
  for (int k = 0; k < 64; k++) {
    float hk = fmaxf(hid[k], 0.f);
#pragma unroll
    for (int j = 0; j < 32; j++) h[j] = fmaf(hk, w2[k*32 + j], h[j]);
  }
}

// Per-wave LDS transpose-stage reduction of kv = sum k (x) v and ksum = sum k.
// Lane (d,e) = (lane>>3, lane&7) owns kv[h][d][e] for all 4 heads.
__device__ __forceinline__ void accum_kv(const float* kk, const float* vv,
                                         float* stg, float* blk, float* gkv, int tid) {
  const int lane = tid & 63;
  const int down = lane >> 3;
  const int eown = lane & 7;
  float kvacc[4], ksacc[4];
#pragma unroll
  for (int hh = 0; hh < 4; hh++) {
#pragma unroll
    for (int j = 0; j < 8; j++) {
      stg[j*STRIDE_ST + lane]       = kk[hh*8 + j];
      stg[(8 + j)*STRIDE_ST + lane] = vv[hh*8 + j];
    }
    __syncthreads();
    float acc = 0.f, ks = 0.f;
#pragma unroll
    for (int p = 0; p < 64; p += 4) {
      const float4 kf = *(const float4*)&stg[down*STRIDE_ST + p];
      const float4 vf = *(const float4*)&stg[(8 + eown)*STRIDE_ST + p];
      acc = fmaf(kf.x, vf.x, acc);
      acc = fmaf(kf.y, vf.y, acc);
      acc = fmaf(kf.z, vf.z, acc);
      acc = fmaf(kf.w, vf.w, acc);
      ks += (kf.x + kf.y) + (kf.z + kf.w);
    }
    kvacc[hh] = acc;
    ksacc[hh] = ks;
    __syncthreads();
  }
#pragma unroll
  for (int hh = 0; hh < 4; hh++)
    atomicAdd(&blk[hh*64 + down*8 + eown], kvacc[hh]);
  if (eown == 0) {
#pragma unroll
    for (int hh = 0; hh < 4; hh++)
      atomicAdd(&blk[256 + hh*8 + down], ksacc[hh]);
  }
  __syncthreads();
  for (int i = tid; i < KVSZ; i += 256) atomicAdd(&gkv[i], blk[i]);
}

// K1: embed -> h0 (to d_out), k/v layer0 -> kv accum
__global__ __launch_bounds__(256, 4) void k_embed(
    const float* __restrict__ x, const float* __restrict__ pos,
    const float* __restrict__ w_in, const float* __restrict__ b_in,
    const float* __restrict__ w_pos, const float* __restrict__ b_pos,
    const float* __restrict__ wk, const float* __restrict__ bk,
    const float* __restrict__ wv, const float* __restrict__ bv,
    float* __restrict__ hout, float* __restrict__ gkv) {
  __shared__ __align__(16) float stage[4 * 16 * STRIDE_ST];
  __shared__ float blk[KVSZ];
  const int tid = threadIdx.x;
  for (int i = tid; i < KVSZ; i += 256) blk[i] = 0.f;
  __syncthreads();

  const int pt = blockIdx.x * 256 + tid;
  const int c  = blockIdx.x >> 7;   // 128 blocks per cloud

  float xin[16];
  const float4* xp = (const float4*)(x + (size_t)pt * 16);
#pragma unroll
  for (int q4 = 0; q4 < 4; q4++) {
    float4 t = xp[q4];
    xin[q4*4] = t.x; xin[q4*4+1] = t.y; xin[q4*4+2] = t.z; xin[q4*4+3] = t.w;
  }
  float p0 = pos[(size_t)pt*3], p1 = pos[(size_t)pt*3+1], p2 = pos[(size_t)pt*3+2];

  float h[32];
#pragma unroll
  for (int j = 0; j < 32; j++) h[j] = b_in[j] + b_pos[j];
#pragma unroll
  for (int k = 0; k < 16; k++) {
    float hk = xin[k];
#pragma unroll
    for (int j = 0; j < 32; j++) h[j] = fmaf(hk, w_in[k*32 + j], h[j]);
  }
#pragma unroll
  for (int j = 0; j < 32; j++) {
    h[j] = fmaf(p0, w_pos[j],      h[j]);
    h[j] = fmaf(p1, w_pos[32 + j], h[j]);
    h[j] = fmaf(p2, w_pos[64 + j], h[j]);
  }
  float4* ho = (float4*)(hout + (size_t)pt * 32);
#pragma unroll
  for (int q4 = 0; q4 < 8; q4++) {
    float4 t; t.x = h[q4*4]; t.y = h[q4*4+1]; t.z = h[q4*4+2]; t.w = h[q4*4+3];
    ho[q4] = t;
  }
  float kk[32], vv[32];
  proj32(h, wk, bk, kk);
  phi32(kk);
  proj32(h, wv, bv, vv);
  accum_kv(kk, vv, stage + (tid >> 6) * (16 * STRIDE_ST), blk, gkv + c * KVSZ, tid);
}

// K2: layer-0 attention+FFN (reads/writes hbuf in place), layer-1 k/v -> kv accum
__global__ __launch_bounds__(256, 4) void k_mid(
    const float* __restrict__ wq, const float* __restrict__ bq,
    const float* __restrict__ wo, const float* __restrict__ bo,
    const float* __restrict__ g1, const float* __restrict__ be1,
    const float* __restrict__ w1, const float* __restrict__ bf1,
    const float* __restrict__ w2, const float* __restrict__ bf2,
    const float* __restrict__ g2, const float* __restrict__ be2,
    const float* __restrict__ wkn, const float* __restrict__ bkn,
    const float* __restrict__ wvn, const float* __restrict__ bvn,
    const float* __restrict__ kv_in, float* __restrict__ gkv_out,
    float* __restrict__ hbuf) {
  __shared__ __align__(16) float stage[4 * 16 * STRIDE_ST];
  __shared__ float blk[KVSZ];
  const int tid = threadIdx.x;
  const int c   = blockIdx.x >> 7;
  for (int i = tid; i < KVSZ; i += 256) blk[i] = 0.f;
  __syncthreads();

  const int pt = blockIdx.x * 256 + tid;
  float h[32];
  const float4* hp = (const float4*)(hbuf + (size_t)pt * 32);
#pragma unroll
  for (int q4 = 0; q4 < 8; q4++) {
    float4 t = hp[q4];
    h[q4*4] = t.x; h[q4*4+1] = t.y; h[q4*4+2] = t.z; h[q4*4+3] = t.w;
  }
  float qv[32];
  proj32(h, wq, bq, qv);
  phi32(qv);
  float attn[32];
  attn_part(qv, kv_in + c * KVSZ, attn);
  proj32_add(attn, wo, bo, h);           // h += attn @ wo + bo
  ln32(h, g1, be1);
  ffn32_add(h, w1, bf1, w2, bf2);        // h += ffn(h)
  ln32(h, g2, be2);
  float4* hpw = (float4*)(hbuf + (size_t)pt * 32);
#pragma unroll
  for (int q4 = 0; q4 < 8; q4++) {
    float4 t; t.x = h[q4*4]; t.y = h[q4*4+1]; t.z = h[q4*4+2]; t.w = h[q4*4+3];
    hpw[q4] = t;
  }
  float kk[32], vv[32];
  proj32(h, wkn, bkn, kk);
  phi32(kk);
  proj32(h, wvn, bvn, vv);
  accum_kv(kk, vv, stage + (tid >> 6) * (16 * STRIDE_ST), blk, gkv_out + c * KVSZ, tid);
}

// K3: layer-1 attention+FFN -> final output (in place in hbuf == d_out); no LDS at all
__global__ __launch_bounds__(256, 4) void k_last(
    const float* __restrict__ wq, const float* __restrict__ bq,
    const float* __restrict__ wo, const float* __restrict__ bo,
    const float* __restrict__ g1, const float* __restrict__ be1,
    const float* __restrict__ w1, const float* __restrict__ bf1,
    const float* __restrict__ w2, const float* __restrict__ bf2,
    const float* __restrict__ g2, const float* __restrict__ be2,
    const float* __restrict__ kv_in, float* __restrict__ hbuf) {
  const int tid = threadIdx.x;
  const int c   = blockIdx.x >> 7;
  const int pt  = blockIdx.x * 256 + tid;
  float h[32];
  const float4* hp = (const float4*)(hbuf + (size_t)pt * 32);
#pragma unroll
  for (int q4 = 0; q4 < 8; q4++) {
    float4 t = hp[q4];
    h[q4*4] = t.x; h[q4*4+1] = t.y; h[q4*4+2] = t.z; h[q4*4+3] = t.w;
  }
  float qv[32];
  proj32(h, wq, bq, qv);
  phi32(qv);
  float attn[32];
  attn_part(qv, kv_in + c * KVSZ, attn);
  proj32_add(attn, wo, bo, h);
  ln32(h, g1, be1);
  ffn32_add(h, w1, bf1, w2, bf2);
  ln32(h, g2, be2);
  float4* hpw = (float4*)(hbuf + (size_t)pt * 32);
#pragma unroll
  for (int q4 = 0; q4 < 8; q4++) {
    float4 t; t.x = h[q4*4]; t.y = h[q4*4+1]; t.z = h[q4*4+2]; t.w = h[q4*4+3];
    hpw[q4] = t;
  }
}

extern "C" void kernel_launch(void* const* d_in, const int* in_sizes, int n_in,
                              void* d_out, int out_size, void* d_ws, size_t ws_size,
                              hipStream_t stream) {
  (void)in_sizes; (void)n_in; (void)out_size; (void)ws_size;
  const float* x     = (const float*)d_in[0];
  const float* pos   = (const float*)d_in[1];
  // d_in[2] = batch (arange//N_PER) -- identity mapping, unused
  const float* w_in  = (const float*)d_in[3];
  const float* b_in  = (const float*)d_in[4];
  const float* w_pos = (const float*)d_in[5];
  const float* b_pos = (const float*)d_in[6];
  const float* wq  = (const float*)d_in[7];
  const float* bq  = (const float*)d_in[8];
  const float* wk  = (const float*)d_in[9];
  const float* bk  = (const float*)d_in[10];
  const float* wv  = (const float*)d_in[11];
  const float* bv  = (const float*)d_in[12];
  const float* wo  = (const float*)d_in[13];
  const float* bo  = (const float*)d_in[14];
  const float* g1  = (const float*)d_in[15];
  const float* be1 = (const float*)d_in[16];
  const float* w1  = (const float*)d_in[17];
  const float* bf1 = (const float*)d_in[18];
  const float* w2  = (const float*)d_in[19];
  const float* bf2 = (const float*)d_in[20];
  const float* g2  = (const float*)d_in[21];
  const float* be2 = (const float*)d_in[22];
  float* out   = (float*)d_out;
  float* kvbuf = (float*)d_ws;   // 2 layers * 16 clouds * 288 floats = 36 KB

  hipMemsetAsync(kvbuf, 0, 2 * 16 * KVSZ * sizeof(float), stream);
  dim3 grid(2048), block(256);
  k_embed<<<grid, block, 0, stream>>>(x, pos, w_in, b_in, w_pos, b_pos,
                                      wk, bk, wv, bv, out, kvbuf);
  k_mid<<<grid, block, 0, stream>>>(wq, bq, wo, bo, g1, be1, w1, bf1, w2, bf2, g2, be2,
                                    wk + 1024, bk + 32, wv + 1024, bv + 32,
                                    kvbuf, kvbuf + 16 * KVSZ, out);
  k_last<<<grid, block, 0, stream>>>(wq + 1024, bq + 32, wo + 1024, bo + 32,
                                     g1 + 32, be1 + 32, w1 + 2048, bf1 + 64,
                                     w2 + 2048, bf2 + 32, g2 + 32, be2 + 32,
                                     kvbuf + 16 * KVSZ, out);
}